// Round 10
// baseline (205.997 us; speedup 1.0000x reference)
//
#include <hip/hip_runtime.h>

#define NUM_NODES 200000
#define DIM 128
#define BATCH 1024
#define K_NEG 5
#define CAP 16
#define NBLK 250          /* sim blocks; 200000 = 250 * 800 */
#define CPB 800           /* columns per block */
#define TCOL 32           /* columns per tile; 800 = 25 * 32 */
#define NT 25             /* tiles per block */
#define THRESH 0.7f
#define FILL (-1.0e9f)

typedef __attribute__((ext_vector_type(8))) short short8;
typedef __attribute__((ext_vector_type(16))) float f32x16;

// round-to-nearest-even float -> bf16 bits (finite inputs only)
__device__ __forceinline__ unsigned short f2bf(float x) {
  unsigned u = __builtin_bit_cast(unsigned, x);
  return (unsigned short)((u + 0x7fffu + ((u >> 16) & 1u)) >> 16);
}

// async global->LDS: 16 bytes per lane; LDS dest = wave-uniform base + lane*16
__device__ __forceinline__ void stage16(const void* g, void* l) {
  __builtin_amdgcn_global_load_lds(
      (const __attribute__((address_space(1))) unsigned int*)g,
      (__attribute__((address_space(3))) unsigned int*)l,
      16, 0, 0);
}

// ---------------- Threefry-2x32 (JAX-compatible) ----------------
__device__ __forceinline__ void tf2x32(unsigned k0, unsigned k1,
                                       unsigned x0, unsigned x1,
                                       unsigned* o0, unsigned* o1) {
  unsigned ks2 = k0 ^ k1 ^ 0x1BD11BDAu;
  unsigned v0 = x0 + k0, v1 = x1 + k1;
#define TFR(r) { v0 += v1; v1 = (v1 << r) | (v1 >> (32 - r)); v1 ^= v0; }
  TFR(13) TFR(15) TFR(26) TFR(6)   v0 += k1;  v1 += ks2 + 1u;
  TFR(17) TFR(29) TFR(16) TFR(24)  v0 += ks2; v1 += k0 + 2u;
  TFR(13) TFR(15) TFR(26) TFR(6)   v0 += k0;  v1 += k1 + 3u;
  TFR(17) TFR(29) TFR(16) TFR(24)  v0 += k1;  v1 += ks2 + 4u;
  TFR(13) TFR(15) TFR(26) TFR(6)   v0 += ks2; v1 += k0 + 5u;
#undef TFR
  *o0 = v0; *o1 = v1;
}

__device__ __forceinline__ unsigned rbits32(unsigned ka, unsigned kb, unsigned m) {
  unsigned o0, o1;
  tf2x32(ka, kb, 0u, m, &o0, &o1);
  return o0 ^ o1;
}

// ---- kernel 1: normalize src rows -> bf16 A-fragments (fragment-major), zero counters
// Fragment layout: chunk ((ms*8 + ks)*64 + lane64) is 8 bf16 (16 B) holding
// A[row = ms*32 + (lane64&31)][col = ks*16 + (lane64>>5)*8 + t], t=0..7.
__global__ void prep_kernel(const float* __restrict__ memory,
                            const int* __restrict__ src_nodes,
                            unsigned short* __restrict__ s16f,
                            int* __restrict__ cand_cnt) {
  int tid = threadIdx.x;
  int gid = blockIdx.x * 256 + tid;
  if (gid < BATCH) cand_cnt[gid] = 0;
  int row = blockIdx.x * 4 + (tid >> 6);   // 256 blocks x 4 waves = 1024 rows
  int L = tid & 63;                        // lane within the row's wave; cols 2L,2L+1
  int s = src_nodes[row];
  float2 v = ((const float2*)(memory + (size_t)s * DIM))[L];
  float ss = v.x * v.x + v.y * v.y;
#pragma unroll
  for (int off = 32; off > 0; off >>= 1) ss += __shfl_xor(ss, off);
  float inv = 1.0f / fmaxf(sqrtf(ss), 1e-12f);
  unsigned p = (unsigned)f2bf(v.x * inv) | ((unsigned)f2bf(v.y * inv) << 16);
  int ms = row >> 5, l32 = row & 31;
  int c = L >> 2;             // col chunk = col/8
  int ks = c >> 1, half = c & 1;
  ((unsigned*)s16f)[(((ms * 8 + ks) * 64) + half * 32 + l32) * 4 + (L & 3)] = p;
}

// ---- kernel 2: read-once MFMA sim scan, 3-stage single-barrier pipeline ----
// A: each of 8 waves holds 4 subtiles in registers (128 VGPR), loaded once.
// B: tile t staged (iter t-2) -> converted (iter t-1) -> MFMA'd (iter t),
// with double raw (2x16KB) and double frag (2x8KB) LDS buffers; ONE barrier
// per iteration. Parity proof: raw[x] holds tiles with t&1==x; iter t writes
// raw[t&1] (tile t+2), reads raw[(t+1)&1] (convert t+1), frag[(t+1)&1]
// written, frag[t&1] read by MFMA -- all disjoint; cross-iter ordering by the
// barrier's full drain. Raw tiles stored with col-XOR swizzle
// (gcol = colf ^ ((seg>>1)&7), both sides) so CONVERT's 16B reads spread over
// all 8 bank-groups (2-way, free). Scale-after-MFMA normalization.
__global__ __launch_bounds__(512, 2) void sim_scan_kernel(
    const float* __restrict__ memory,
    const unsigned short* __restrict__ s16f,
    const int* __restrict__ dst_nodes,
    int* __restrict__ cand_cnt,
    float* __restrict__ cand_val,
    int* __restrict__ cand_idx) {
  __shared__ char rawb[2][16384];            // raw fp32 tiles, [seg32][colf32] x 16 B, swizzled
  __shared__ unsigned short fragb[2][4096];  // bf16 frags, [seg16][col32] x 16 B
  __shared__ float nrmb[2][32];              // per-column L2 norms

  int tid = threadIdx.x;
  int wid = tid >> 6;
  int lane = tid & 63;
  int half = lane >> 5;
  int l32 = lane & 31;
  int jb0 = blockIdx.x * CPB;

  const char* mb = (const char*)memory;

  // stage tile t into raw buffer: unit u (0..1023) -> LDS u*16; global column
  // gcol = (u&31) ^ ((u>>6)&7)  [seg = u>>5; swizzle key = (seg>>1)&7]
#define STAGE(t, rbuf) {                                                        \
    int jn = jb0 + (t) * TCOL;                                                  \
    int u1 = tid;                                                               \
    int g1 = (u1 & 31) ^ ((u1 >> 6) & 7);                                       \
    stage16(mb + (size_t)(jn + g1) * 512 + ((u1 >> 5) << 4),                    \
            (char*)(rbuf) + (wid << 10));                                       \
    int u2 = tid + 512;                                                         \
    int g2 = (u2 & 31) ^ ((u2 >> 6) & 7);                                       \
    stage16(mb + (size_t)(jn + g2) * 512 + ((u2 >> 5) << 4),                    \
            (char*)(rbuf) + 8192 + (wid << 10));                                \
  }

  // convert own 4 columns of raw tile into frag[p]/nrm[p]
  int ccol = wid * 4 + (lane & 3);   // col 0..31 (per wave: 4 cols)
  int cseg = lane >> 2;              // seg-pair 0..15 (elements [cseg*8, cseg*8+8))
#define CONVERT(p, rbuf) {                                                      \
    const char* rb = (const char*)(rbuf);                                       \
    int xc = ccol ^ (cseg & 7);                                                 \
    float4 q0 = *(const float4*)(rb + (((2 * cseg) * 32 + xc) << 4));           \
    float4 q1 = *(const float4*)(rb + (((2 * cseg + 1) * 32 + xc) << 4));       \
    float ss = q0.x * q0.x + q0.y * q0.y + q0.z * q0.z + q0.w * q0.w            \
             + q1.x * q1.x + q1.y * q1.y + q1.z * q1.z + q1.w * q1.w;           \
    ss += __shfl_xor(ss, 4); ss += __shfl_xor(ss, 8);                           \
    ss += __shfl_xor(ss, 16); ss += __shfl_xor(ss, 32);                         \
    short8 f;                                                                   \
    f[0] = (short)f2bf(q0.x); f[1] = (short)f2bf(q0.y);                         \
    f[2] = (short)f2bf(q0.z); f[3] = (short)f2bf(q0.w);                         \
    f[4] = (short)f2bf(q1.x); f[5] = (short)f2bf(q1.y);                         \
    f[6] = (short)f2bf(q1.z); f[7] = (short)f2bf(q1.w);                         \
    *(short8*)((char*)fragb[p] + ((cseg * 32 + ccol) << 4)) = f;                \
    if (cseg == 0) nrmb[p][ccol] = fmaxf(sqrtf(ss), 1e-12f);                    \
  }

  // ---- prologue: stage t0; A-load; convert t0; stage t1 ----
  STAGE(0, rawb[0]);
  const short8* __restrict__ af = (const short8*)s16f;
  short8 a[4][8];
#pragma unroll
  for (int m = 0; m < 4; ++m)
#pragma unroll
    for (int ks = 0; ks < 8; ++ks)
      a[m][ks] = af[(((wid * 4 + m) * 8) + ks) * 64 + lane];
  __syncthreads();          // raw0 (tile 0) resident
  CONVERT(0, rawb[0]);
  STAGE(1, rawb[1]);
  __syncthreads();          // frag0 visible; raw1 (tile 1) resident

  f32x16 Z;
#pragma unroll
  for (int i = 0; i < 16; ++i) Z[i] = 0.0f;

  // ---- main loop: one barrier per tile ----
  for (int t = 0; t < NT; ++t) {
    int par = t & 1;
    if (t + 2 < NT) STAGE(t + 2, rawb[par]);            // tile t's raw is dead
    if (t + 1 < NT) CONVERT(par ^ 1, rawb[par ^ 1]);    // tile t+1 raw -> frag

    // ---- MFMA phase on frag[par] ----
    float nv = nrmb[par][l32];
    float thr = THRESH * nv;
    float invv = 1.0f / nv;
    int gj = jb0 + t * TCOL + l32;
    short8 bf[8];
#pragma unroll
    for (int ks = 0; ks < 8; ++ks)
      bf[ks] = *(const short8*)((char*)fragb[par] + (((2 * ks + half) * 32 + l32) << 4));

#pragma unroll
    for (int mp = 0; mp < 2; ++mp) {
      f32x16 accA = __builtin_amdgcn_mfma_f32_32x32x16_bf16(a[mp * 2][0], bf[0], Z, 0, 0, 0);
      f32x16 accB = __builtin_amdgcn_mfma_f32_32x32x16_bf16(a[mp * 2 + 1][0], bf[0], Z, 0, 0, 0);
#pragma unroll
      for (int ks = 1; ks < 8; ++ks) {
        accA = __builtin_amdgcn_mfma_f32_32x32x16_bf16(a[mp * 2][ks], bf[ks], accA, 0, 0, 0);
        accB = __builtin_amdgcn_mfma_f32_32x32x16_bf16(a[mp * 2 + 1][ks], bf[ks], accB, 0, 0, 0);
      }
      float mA = accA[0], mB = accB[0];
#pragma unroll
      for (int i = 1; i < 16; ++i) { mA = fmaxf(mA, accA[i]); mB = fmaxf(mB, accB[i]); }
      if (mA > thr || mB > thr) {
        // C/D layout (m74/m101): col=lane&31, row=(r&3)+8*(r>>2)+4*(lane>>5)
#pragma unroll
        for (int e = 0; e < 2; ++e) {
#pragma unroll
          for (int r = 0; r < 16; ++r) {
            float raw = (e == 0) ? accA[r] : accB[r];
            if (raw > thr) {
              int gi = (wid * 4 + mp * 2 + e) * 32 + (r & 3) + 8 * (r >> 2) + 4 * half;
              if (gj != dst_nodes[gi]) {
                int pq = atomicAdd(&cand_cnt[gi], 1);
                if (pq < CAP) {
                  cand_val[gi * CAP + pq] = raw * invv;
                  cand_idx[gi * CAP + pq] = gj;
                }
              }
            }
          }
        }
      }
    }

    __syncthreads();   // drains: stage into raw[par], convert writes to frag[par^1]
  }
#undef STAGE
#undef CONVERT
}

// ---- kernel 3: top-5 per row, threefry negatives, assemble ----
__global__ void finalize_kernel(const int* __restrict__ src_nodes,
                                const int* __restrict__ dst_nodes,
                                const float* __restrict__ labels,
                                const float* __restrict__ ts,
                                const int* __restrict__ cand_cnt,
                                const float* __restrict__ cand_val,
                                const int* __restrict__ cand_idx,
                                float* __restrict__ out) {
  int r = blockIdx.x * 256 + threadIdx.x;
  if (r >= BATCH) return;
  const int TOT = BATCH + BATCH * K_NEG;  // 6144
  int srcv = src_nodes[r];
  float tsv = ts[r];
  out[r] = (float)srcv;
  out[TOT + r] = (float)dst_nodes[r];
  float l = labels[r];
  out[2 * TOT + r] = l * 0.9f + (1.0f - l) * 0.1f;
  out[3 * TOT + r] = tsv;

  int cnt = cand_cnt[r];
  cnt = cnt < CAP ? cnt : CAP;
  float cv[CAP]; int ci[CAP];
  for (int i = 0; i < cnt; ++i) { cv[i] = cand_val[r * CAP + i]; ci[i] = cand_idx[r * CAP + i]; }

  // jax.random.split(key(42)) — partitionable/foldlike: k_i = threefry(key, 0, i)
  unsigned k1a, k1b, k2a, k2b;
  tf2x32(0u, 42u, 0u, 0u, &k1a, &k1b);
  tf2x32(0u, 42u, 0u, 1u, &k2a, &k2b);

  const unsigned span = 200000u;
  const unsigned mult = 167296u;  // 2^32 % span

  for (int s = 0; s < K_NEG; ++s) {
    int sel = -1;
    for (int i = 0; i < cnt; ++i)
      if (sel < 0 || cv[i] > cv[sel] || (cv[i] == cv[sel] && ci[i] < ci[sel])) sel = i;
    float v = FILL; int idx = 0;
    if (sel >= 0) { v = cv[sel]; idx = ci[sel]; cv[sel] = FILL; ci[sel] = 0x7fffffff; }
    bool is_real = v > (FILL + 1.0f);

    unsigned m = (unsigned)(r * K_NEG + s);
    unsigned hi = rbits32(k1a, k1b, m);
    unsigned lo = rbits32(k2a, k2b, m);
    unsigned off = ((hi % span) * mult + (lo % span)) % span;  // uint32 wrap, as JAX
    int rd = (int)off;
    if (rd == srcv) rd = (rd + 1) % NUM_NODES;
    int fd = is_real ? idx : rd;

    int mi = (int)m;
    out[BATCH + mi] = (float)srcv;
    out[TOT + BATCH + mi] = (float)fd;
    out[2 * TOT + BATCH + mi] = 0.1f;   // smoothing of label 0
    out[3 * TOT + BATCH + mi] = tsv;
    out[4 * TOT + mi] = v;
  }
}

extern "C" void kernel_launch(void* const* d_in, const int* in_sizes, int n_in,
                              void* d_out, int out_size, void* d_ws, size_t ws_size,
                              hipStream_t stream) {
  const int* src = (const int*)d_in[0];
  const int* dst = (const int*)d_in[1];
  const float* labels = (const float*)d_in[2];
  const float* ts = (const float*)d_in[3];
  const float* memory = (const float*)d_in[4];
  float* out = (float*)d_out;

  char* ws = (char*)d_ws;
  unsigned short* s16f = (unsigned short*)ws;       // 1024*128*2 = 262144 B (fragment-major)
  int* cand_cnt = (int*)(ws + 262144);              // 4096 B
  float* cand_val = (float*)(ws + 266240);          // 65536 B
  int* cand_idx = (int*)(ws + 331776);              // 65536 B

  prep_kernel<<<256, 256, 0, stream>>>(memory, src, s16f, cand_cnt);
  sim_scan_kernel<<<NBLK, 512, 0, stream>>>(memory, s16f, dst, cand_cnt, cand_val, cand_idx);
  finalize_kernel<<<(BATCH + 255) / 256, 256, 0, stream>>>(src, dst, labels, ts,
                                                           cand_cnt, cand_val, cand_idx, out);
}

// Round 11
// 188.297 us; speedup vs baseline: 1.0940x; 1.0940x over previous
//
#include <hip/hip_runtime.h>

#define NUM_NODES 200000
#define DIM 128
#define BATCH 1024
#define K_NEG 5
#define CAP 16
#define NBLK 250          /* sim blocks; 200000 = 250 * 800 */
#define CPB 800           /* columns per block */
#define TCOL 32           /* columns per tile; 800 = 25 * 32 */
#define NT 25             /* tiles per block */
#define THRESH 0.7f
#define FILL (-1.0e9f)

typedef __attribute__((ext_vector_type(8))) short short8;
typedef __attribute__((ext_vector_type(16))) float f32x16;

// round-to-nearest-even float -> bf16 bits (finite inputs only)
__device__ __forceinline__ unsigned short f2bf(float x) {
  unsigned u = __builtin_bit_cast(unsigned, x);
  return (unsigned short)((u + 0x7fffu + ((u >> 16) & 1u)) >> 16);
}

// ---------------- Threefry-2x32 (JAX-compatible) ----------------
__device__ __forceinline__ void tf2x32(unsigned k0, unsigned k1,
                                       unsigned x0, unsigned x1,
                                       unsigned* o0, unsigned* o1) {
  unsigned ks2 = k0 ^ k1 ^ 0x1BD11BDAu;
  unsigned v0 = x0 + k0, v1 = x1 + k1;
#define TFR(r) { v0 += v1; v1 = (v1 << r) | (v1 >> (32 - r)); v1 ^= v0; }
  TFR(13) TFR(15) TFR(26) TFR(6)   v0 += k1;  v1 += ks2 + 1u;
  TFR(17) TFR(29) TFR(16) TFR(24)  v0 += ks2; v1 += k0 + 2u;
  TFR(13) TFR(15) TFR(26) TFR(6)   v0 += k0;  v1 += k1 + 3u;
  TFR(17) TFR(29) TFR(16) TFR(24)  v0 += k1;  v1 += ks2 + 4u;
  TFR(13) TFR(15) TFR(26) TFR(6)   v0 += ks2; v1 += k0 + 5u;
#undef TFR
  *o0 = v0; *o1 = v1;
}

__device__ __forceinline__ unsigned rbits32(unsigned ka, unsigned kb, unsigned m) {
  unsigned o0, o1;
  tf2x32(ka, kb, 0u, m, &o0, &o1);
  return o0 ^ o1;
}

// ---- kernel 1: normalize src rows -> bf16 A-fragments (fragment-major), zero counters
// Fragment layout: chunk ((ms*8 + ks)*64 + lane64) is 8 bf16 (16 B) holding
// A[row = ms*32 + (lane64&31)][col = ks*16 + (lane64>>5)*8 + t], t=0..7.
__global__ void prep_kernel(const float* __restrict__ memory,
                            const int* __restrict__ src_nodes,
                            unsigned short* __restrict__ s16f,
                            int* __restrict__ cand_cnt) {
  int tid = threadIdx.x;
  int gid = blockIdx.x * 256 + tid;
  if (gid < BATCH) cand_cnt[gid] = 0;
  int row = blockIdx.x * 4 + (tid >> 6);   // 256 blocks x 4 waves = 1024 rows
  int L = tid & 63;                        // lane within the row's wave; cols 2L,2L+1
  int s = src_nodes[row];
  float2 v = ((const float2*)(memory + (size_t)s * DIM))[L];
  float ss = v.x * v.x + v.y * v.y;
#pragma unroll
  for (int off = 32; off > 0; off >>= 1) ss += __shfl_xor(ss, off);
  float inv = 1.0f / fmaxf(sqrtf(ss), 1e-12f);
  unsigned p = (unsigned)f2bf(v.x * inv) | ((unsigned)f2bf(v.y * inv) << 16);
  int ms = row >> 5, l32 = row & 31;
  int c = L >> 2;             // col chunk = col/8
  int ks = c >> 1, half = c & 1;
  ((unsigned*)s16f)[(((ms * 8 + ks) * 64) + half * 32 + l32) * 4 + (L & 3)] = p;
}

// ---- kernel 2: read-once MFMA sim scan, register-prefetch + convert-once ----
// A: each of 8 waves holds 4 subtiles in registers (128 VGPR), loaded once.
// B: NO raw LDS staging. Each wave owns 4 columns of each 32-col tile; it
// issues 2 contiguous float4 global loads (32 B/lane; wave = 4 full rows,
// coalesced) for tile t+1 BEFORE the MFMA phase of tile t, and converts the
// registers to bf16 frags + column norms AFTER it (T14 async-split: HBM
// latency hides under ~600 cyc of MFMA). Converted frags are shared via a
// double-buffered 8 KB LDS frag buffer; one barrier per tile. Scale-after-
// MFMA normalization: acc > 0.7*|b_j|, value = acc/|b_j|.
__global__ __launch_bounds__(512, 2) void sim_scan_kernel(
    const float* __restrict__ memory,
    const unsigned short* __restrict__ s16f,
    const int* __restrict__ dst_nodes,
    int* __restrict__ cand_cnt,
    float* __restrict__ cand_val,
    int* __restrict__ cand_idx) {
  __shared__ unsigned short fragb[2][4096];  // bf16 frags, [seg16][col32] x 16 B
  __shared__ float nrmb[2][32];              // per-column L2 norms

  int tid = threadIdx.x;
  int wid = tid >> 6;
  int lane = tid & 63;
  int half = lane >> 5;
  int l32 = lane & 31;
  int jb0 = blockIdx.x * CPB;

  int ccol = wid * 4 + (lane & 3);   // this lane's owned column (0..31 in tile)
  int cseg = lane >> 2;              // element group [cseg*8, cseg*8+8)

  // convert held registers -> frag[p]/nrm[p] for own column
#define CONVERT(p, q0, q1) {                                                    \
    float ss = q0.x * q0.x + q0.y * q0.y + q0.z * q0.z + q0.w * q0.w            \
             + q1.x * q1.x + q1.y * q1.y + q1.z * q1.z + q1.w * q1.w;           \
    ss += __shfl_xor(ss, 4); ss += __shfl_xor(ss, 8);                           \
    ss += __shfl_xor(ss, 16); ss += __shfl_xor(ss, 32);                         \
    short8 f;                                                                   \
    f[0] = (short)f2bf(q0.x); f[1] = (short)f2bf(q0.y);                         \
    f[2] = (short)f2bf(q0.z); f[3] = (short)f2bf(q0.w);                         \
    f[4] = (short)f2bf(q1.x); f[5] = (short)f2bf(q1.y);                         \
    f[6] = (short)f2bf(q1.z); f[7] = (short)f2bf(q1.w);                         \
    *(short8*)((char*)fragb[p] + ((cseg * 32 + ccol) << 4)) = f;                \
    if (cseg == 0) nrmb[p][ccol] = fmaxf(sqrtf(ss), 1e-12f);                    \
  }

  // ---- prologue: load tile0 cols -> regs; A-frags; convert t0; barrier ----
  float4 q0, q1;
  {
    const float4* rp4 = (const float4*)(memory + (size_t)(jb0 + ccol) * DIM);
    q0 = rp4[cseg * 2];
    q1 = rp4[cseg * 2 + 1];
  }
  const short8* __restrict__ af = (const short8*)s16f;
  short8 a[4][8];
#pragma unroll
  for (int m = 0; m < 4; ++m)
#pragma unroll
    for (int ks = 0; ks < 8; ++ks)
      a[m][ks] = af[(((wid * 4 + m) * 8) + ks) * 64 + lane];
  CONVERT(0, q0, q1);
  __syncthreads();          // frag[0] visible

  f32x16 Z;
#pragma unroll
  for (int i = 0; i < 16; ++i) Z[i] = 0.0f;

  // ---- main loop: one barrier per tile ----
  for (int t = 0; t < NT; ++t) {
    int par = t & 1;

    // (a) issue next tile's loads into registers (no wait; lands under MFMA)
    if (t + 1 < NT) {
      const float4* rp4 =
          (const float4*)(memory + (size_t)(jb0 + (t + 1) * TCOL + ccol) * DIM);
      q0 = rp4[cseg * 2];
      q1 = rp4[cseg * 2 + 1];
    }

    // (b) MFMA phase on frag[par]
    float nv = nrmb[par][l32];
    float thr = THRESH * nv;
    float invv = 1.0f / nv;
    int gj = jb0 + t * TCOL + l32;
    short8 bf[8];
#pragma unroll
    for (int ks = 0; ks < 8; ++ks)
      bf[ks] = *(const short8*)((char*)fragb[par] + (((2 * ks + half) * 32 + l32) << 4));

#pragma unroll
    for (int mp = 0; mp < 2; ++mp) {
      f32x16 accA = __builtin_amdgcn_mfma_f32_32x32x16_bf16(a[mp * 2][0], bf[0], Z, 0, 0, 0);
      f32x16 accB = __builtin_amdgcn_mfma_f32_32x32x16_bf16(a[mp * 2 + 1][0], bf[0], Z, 0, 0, 0);
#pragma unroll
      for (int ks = 1; ks < 8; ++ks) {
        accA = __builtin_amdgcn_mfma_f32_32x32x16_bf16(a[mp * 2][ks], bf[ks], accA, 0, 0, 0);
        accB = __builtin_amdgcn_mfma_f32_32x32x16_bf16(a[mp * 2 + 1][ks], bf[ks], accB, 0, 0, 0);
      }
      float mA = accA[0], mB = accB[0];
#pragma unroll
      for (int i = 1; i < 16; ++i) { mA = fmaxf(mA, accA[i]); mB = fmaxf(mB, accB[i]); }
      if (mA > thr || mB > thr) {
        // C/D layout (m74/m101): col=lane&31, row=(r&3)+8*(r>>2)+4*(lane>>5)
#pragma unroll
        for (int e = 0; e < 2; ++e) {
#pragma unroll
          for (int r = 0; r < 16; ++r) {
            float raw = (e == 0) ? accA[r] : accB[r];
            if (raw > thr) {
              int gi = (wid * 4 + mp * 2 + e) * 32 + (r & 3) + 8 * (r >> 2) + 4 * half;
              if (gj != dst_nodes[gi]) {
                int pq = atomicAdd(&cand_cnt[gi], 1);
                if (pq < CAP) {
                  cand_val[gi * CAP + pq] = raw * invv;
                  cand_idx[gi * CAP + pq] = gj;
                }
              }
            }
          }
        }
      }
    }

    // (c) convert prefetched registers -> frag[par^1] (write-late)
    if (t + 1 < NT) CONVERT(par ^ 1, q0, q1);

    // (d) barrier: frag[par^1] visible; frag[par] free for overwrite at t+2
    __syncthreads();
  }
#undef CONVERT
}

// ---- kernel 3: top-5 per row, threefry negatives, assemble ----
__global__ void finalize_kernel(const int* __restrict__ src_nodes,
                                const int* __restrict__ dst_nodes,
                                const float* __restrict__ labels,
                                const float* __restrict__ ts,
                                const int* __restrict__ cand_cnt,
                                const float* __restrict__ cand_val,
                                const int* __restrict__ cand_idx,
                                float* __restrict__ out) {
  int r = blockIdx.x * 256 + threadIdx.x;
  if (r >= BATCH) return;
  const int TOT = BATCH + BATCH * K_NEG;  // 6144
  int srcv = src_nodes[r];
  float tsv = ts[r];
  out[r] = (float)srcv;
  out[TOT + r] = (float)dst_nodes[r];
  float l = labels[r];
  out[2 * TOT + r] = l * 0.9f + (1.0f - l) * 0.1f;
  out[3 * TOT + r] = tsv;

  int cnt = cand_cnt[r];
  cnt = cnt < CAP ? cnt : CAP;
  float cv[CAP]; int ci[CAP];
  for (int i = 0; i < cnt; ++i) { cv[i] = cand_val[r * CAP + i]; ci[i] = cand_idx[r * CAP + i]; }

  // jax.random.split(key(42)) — partitionable/foldlike: k_i = threefry(key, 0, i)
  unsigned k1a, k1b, k2a, k2b;
  tf2x32(0u, 42u, 0u, 0u, &k1a, &k1b);
  tf2x32(0u, 42u, 0u, 1u, &k2a, &k2b);

  const unsigned span = 200000u;
  const unsigned mult = 167296u;  // 2^32 % span

  for (int s = 0; s < K_NEG; ++s) {
    int sel = -1;
    for (int i = 0; i < cnt; ++i)
      if (sel < 0 || cv[i] > cv[sel] || (cv[i] == cv[sel] && ci[i] < ci[sel])) sel = i;
    float v = FILL; int idx = 0;
    if (sel >= 0) { v = cv[sel]; idx = ci[sel]; cv[sel] = FILL; ci[sel] = 0x7fffffff; }
    bool is_real = v > (FILL + 1.0f);

    unsigned m = (unsigned)(r * K_NEG + s);
    unsigned hi = rbits32(k1a, k1b, m);
    unsigned lo = rbits32(k2a, k2b, m);
    unsigned off = ((hi % span) * mult + (lo % span)) % span;  // uint32 wrap, as JAX
    int rd = (int)off;
    if (rd == srcv) rd = (rd + 1) % NUM_NODES;
    int fd = is_real ? idx : rd;

    int mi = (int)m;
    out[BATCH + mi] = (float)srcv;
    out[TOT + BATCH + mi] = (float)fd;
    out[2 * TOT + BATCH + mi] = 0.1f;   // smoothing of label 0
    out[3 * TOT + BATCH + mi] = tsv;
    out[4 * TOT + mi] = v;
  }
}

extern "C" void kernel_launch(void* const* d_in, const int* in_sizes, int n_in,
                              void* d_out, int out_size, void* d_ws, size_t ws_size,
                              hipStream_t stream) {
  const int* src = (const int*)d_in[0];
  const int* dst = (const int*)d_in[1];
  const float* labels = (const float*)d_in[2];
  const float* ts = (const float*)d_in[3];
  const float* memory = (const float*)d_in[4];
  float* out = (float*)d_out;

  char* ws = (char*)d_ws;
  unsigned short* s16f = (unsigned short*)ws;       // 1024*128*2 = 262144 B (fragment-major)
  int* cand_cnt = (int*)(ws + 262144);              // 4096 B
  float* cand_val = (float*)(ws + 266240);          // 65536 B
  int* cand_idx = (int*)(ws + 331776);              // 65536 B

  prep_kernel<<<256, 256, 0, stream>>>(memory, src, s16f, cand_cnt);
  sim_scan_kernel<<<NBLK, 512, 0, stream>>>(memory, s16f, dst, cand_cnt, cand_val, cand_idx);
  finalize_kernel<<<(BATCH + 255) / 256, 256, 0, stream>>>(src, dst, labels, ts,
                                                           cand_cnt, cand_val, cand_idx, out);
}

// Round 13
// 183.435 us; speedup vs baseline: 1.1230x; 1.0265x over previous
//
#include <hip/hip_runtime.h>

#define NUM_NODES 200000
#define DIM 128
#define BATCH 1024
#define K_NEG 5
#define CAP 16
#define NBLK 250          /* sim blocks; 200000 = 250 * 800 */
#define CPB 800           /* columns per block */
#define TCOL 32           /* columns per tile; 800 = 25 * 32 */
#define NT 25             /* tiles per block */
#define THRESH 0.7f
#define FILL (-1.0e9f)

typedef __attribute__((ext_vector_type(8))) short short8;
typedef __attribute__((ext_vector_type(16))) float f32x16;

// round-to-nearest-even float -> bf16 bits (finite inputs only)
__device__ __forceinline__ unsigned short f2bf(float x) {
  unsigned u = __builtin_bit_cast(unsigned, x);
  return (unsigned short)((u + 0x7fffu + ((u >> 16) & 1u)) >> 16);
}

// async global->LDS: 16 bytes per lane; lane i lands at ldsbase + i*16
__device__ __forceinline__ void stage16(const void* g, void* l) {
  __builtin_amdgcn_global_load_lds(
      (const __attribute__((address_space(1))) unsigned int*)g,
      (__attribute__((address_space(3))) unsigned int*)l,
      16, 0, 0);
}

// ---------------- Threefry-2x32 (JAX-compatible) ----------------
__device__ __forceinline__ void tf2x32(unsigned k0, unsigned k1,
                                       unsigned x0, unsigned x1,
                                       unsigned* o0, unsigned* o1) {
  unsigned ks2 = k0 ^ k1 ^ 0x1BD11BDAu;
  unsigned v0 = x0 + k0, v1 = x1 + k1;
#define TFR(r) { v0 += v1; v1 = (v1 << r) | (v1 >> (32 - r)); v1 ^= v0; }
  TFR(13) TFR(15) TFR(26) TFR(6)   v0 += k1;  v1 += ks2 + 1u;
  TFR(17) TFR(29) TFR(16) TFR(24)  v0 += ks2; v1 += k0 + 2u;
  TFR(13) TFR(15) TFR(26) TFR(6)   v0 += k0;  v1 += k1 + 3u;
  TFR(17) TFR(29) TFR(16) TFR(24)  v0 += k1;  v1 += ks2 + 4u;
  TFR(13) TFR(15) TFR(26) TFR(6)   v0 += ks2; v1 += k0 + 5u;
#undef TFR
  *o0 = v0; *o1 = v1;
}

__device__ __forceinline__ unsigned rbits32(unsigned ka, unsigned kb, unsigned m) {
  unsigned o0, o1;
  tf2x32(ka, kb, 0u, m, &o0, &o1);
  return o0 ^ o1;
}

// ---- kernel 1: normalize src rows -> bf16 A-fragments (fragment-major), zero counters
// Fragment layout: chunk ((ms*8 + ks)*64 + lane64) is 8 bf16 (16 B) holding
// A[row = ms*32 + (lane64&31)][col = ks*16 + (lane64>>5)*8 + t], t=0..7.
__global__ void prep_kernel(const float* __restrict__ memory,
                            const int* __restrict__ src_nodes,
                            unsigned short* __restrict__ s16f,
                            int* __restrict__ cand_cnt) {
  int tid = threadIdx.x;
  int gid = blockIdx.x * 256 + tid;
  if (gid < BATCH) cand_cnt[gid] = 0;
  int row = blockIdx.x * 4 + (tid >> 6);   // 256 blocks x 4 waves = 1024 rows
  int L = tid & 63;                        // lane within the row's wave; cols 2L,2L+1
  int s = src_nodes[row];
  float2 v = ((const float2*)(memory + (size_t)s * DIM))[L];
  float ss = v.x * v.x + v.y * v.y;
#pragma unroll
  for (int off = 32; off > 0; off >>= 1) ss += __shfl_xor(ss, off);
  float inv = 1.0f / fmaxf(sqrtf(ss), 1e-12f);
  unsigned p = (unsigned)f2bf(v.x * inv) | ((unsigned)f2bf(v.y * inv) << 16);
  int ms = row >> 5, l32 = row & 31;
  int c = L >> 2;             // col chunk = col/8
  int ks = c >> 1, half = c & 1;
  ((unsigned*)s16f)[(((ms * 8 + ks) * 64) + half * 32 + l32) * 4 + (L & 3)] = p;
}

// ---- kernel 2: read-once MFMA sim scan, per-wave DMA staging ----
// A: each of 8 waves holds 4 subtiles in registers (128 VGPR), loaded once.
// B: each wave owns 4 columns of each 32-col tile. Tile t+1's 2 KB is staged
// via global_load_lds into a WAVE-PRIVATE LDS slot, issued BEFORE tile t's
// MFMA phase (DMA has no reg dest -> issues in program order, zero VGPR cost,
// cannot be compiler-sunk). After the MFMA phase the wave does its OWN
// s_waitcnt vmcnt(0) (no barrier needed for private data), reads back 32 B
// lane-linearly (conflict-free), converts to bf16 frags + column norms into
// the double-buffered frag LDS (XOR-swizzled chunks, both sides). One block
// barrier per tile publishes frags. Scale-after-MFMA: acc > 0.7*|b_j|,
// value = acc/|b_j|.
__global__ __launch_bounds__(512, 2) void sim_scan_kernel(
    const float* __restrict__ memory,
    const unsigned short* __restrict__ s16f,
    const int* __restrict__ dst_nodes,
    int* __restrict__ cand_cnt,
    float* __restrict__ cand_val,
    int* __restrict__ cand_idx) {
  __shared__ char qbuf[8][2048];             // per-wave staged raw cols (single buffer)
  __shared__ unsigned short fragb[2][4096];  // bf16 frags, [seg16][col32^swz] x 16 B
  __shared__ float nrmb[2][32];              // per-column L2 norms

  int tid = threadIdx.x;
  int wid = tid >> 6;
  int lane = tid & 63;
  int half = lane >> 5;
  int l32 = lane & 31;
  int jb0 = blockIdx.x * CPB;

  int ccol = wid * 4 + (lane & 3);   // this lane's owned column (0..31 in tile)
  int cseg = lane >> 2;              // element group [cseg*8, cseg*8+8)

  const char* mb = (const char*)memory;

  // stage tile t's own-4-columns into this wave's private qbuf slot.
  // lane L: global = row(jb0 + t*32 + wid*4 + (L&3)) + (L>>2)*32 [+16]
  // LDS: qbuf[wid][L*16] and qbuf[wid][1024 + L*16] (HW lane scatter).
#define QSTAGE(t) {                                                             \
    const char* g = mb + (size_t)(jb0 + (t) * TCOL + ccol) * 512 + (cseg << 5); \
    stage16(g, &qbuf[wid][0]);                                                  \
    stage16(g + 16, &qbuf[wid][1024]);                                          \
  }

  // per-wave wait for own DMA, read back own 32 B, convert -> frag[p]/nrm[p]
#define QCONVERT(p) {                                                           \
    asm volatile("s_waitcnt vmcnt(0)" ::: "memory");                            \
    __builtin_amdgcn_sched_barrier(0);                                          \
    float4 q0 = *(const float4*)(&qbuf[wid][lane << 4]);                        \
    float4 q1 = *(const float4*)(&qbuf[wid][1024 + (lane << 4)]);               \
    float ss = q0.x * q0.x + q0.y * q0.y + q0.z * q0.z + q0.w * q0.w            \
             + q1.x * q1.x + q1.y * q1.y + q1.z * q1.z + q1.w * q1.w;           \
    ss += __shfl_xor(ss, 4); ss += __shfl_xor(ss, 8);                           \
    ss += __shfl_xor(ss, 16); ss += __shfl_xor(ss, 32);                         \
    short8 f;                                                                   \
    f[0] = (short)f2bf(q0.x); f[1] = (short)f2bf(q0.y);                         \
    f[2] = (short)f2bf(q0.z); f[3] = (short)f2bf(q0.w);                         \
    f[4] = (short)f2bf(q1.x); f[5] = (short)f2bf(q1.y);                         \
    f[6] = (short)f2bf(q1.z); f[7] = (short)f2bf(q1.w);                         \
    *(short8*)((char*)fragb[p] + ((cseg * 32 + (ccol ^ (cseg & 7))) << 4)) = f; \
    if (cseg == 0) nrmb[p][ccol] = fmaxf(sqrtf(ss), 1e-12f);                    \
  }

  // ---- prologue: stage tile0 (DMA), load A-frags, convert t0, barrier ----
  QSTAGE(0);
  const short8* __restrict__ af = (const short8*)s16f;
  short8 a[4][8];
#pragma unroll
  for (int m = 0; m < 4; ++m)
#pragma unroll
    for (int ks = 0; ks < 8; ++ks)
      a[m][ks] = af[(((wid * 4 + m) * 8) + ks) * 64 + lane];
  QCONVERT(0);
  __syncthreads();          // frag[0] visible

  f32x16 Z;
#pragma unroll
  for (int i = 0; i < 16; ++i) Z[i] = 0.0f;

  // ---- main loop: one barrier per tile ----
  for (int t = 0; t < NT; ++t) {
    int par = t & 1;

    // (a) issue next tile's DMA into own qbuf slot (program-order issue)
    if (t + 1 < NT) QSTAGE(t + 1);

    // (b) MFMA phase on frag[par]
    float nv = nrmb[par][l32];
    float thr = THRESH * nv;
    float invv = 1.0f / nv;
    int gj = jb0 + t * TCOL + l32;
    short8 bf[8];
#pragma unroll
    for (int ks = 0; ks < 8; ++ks) {
      int s0 = 2 * ks + half;
      bf[ks] = *(const short8*)((char*)fragb[par] + ((s0 * 32 + (l32 ^ (s0 & 7))) << 4));
    }

#pragma unroll
    for (int mp = 0; mp < 2; ++mp) {
      f32x16 accA = __builtin_amdgcn_mfma_f32_32x32x16_bf16(a[mp * 2][0], bf[0], Z, 0, 0, 0);
      f32x16 accB = __builtin_amdgcn_mfma_f32_32x32x16_bf16(a[mp * 2 + 1][0], bf[0], Z, 0, 0, 0);
#pragma unroll
      for (int ks = 1; ks < 8; ++ks) {
        accA = __builtin_amdgcn_mfma_f32_32x32x16_bf16(a[mp * 2][ks], bf[ks], accA, 0, 0, 0);
        accB = __builtin_amdgcn_mfma_f32_32x32x16_bf16(a[mp * 2 + 1][ks], bf[ks], accB, 0, 0, 0);
      }
      float mA = accA[0], mB = accB[0];
#pragma unroll
      for (int i = 1; i < 16; ++i) { mA = fmaxf(mA, accA[i]); mB = fmaxf(mB, accB[i]); }
      if (mA > thr || mB > thr) {
        // C/D layout (m74/m101): col=lane&31, row=(r&3)+8*(r>>2)+4*(lane>>5)
#pragma unroll
        for (int e = 0; e < 2; ++e) {
#pragma unroll
          for (int r = 0; r < 16; ++r) {
            float raw = (e == 0) ? accA[r] : accB[r];
            if (raw > thr) {
              int gi = (wid * 4 + mp * 2 + e) * 32 + (r & 3) + 8 * (r >> 2) + 4 * half;
              if (gj != dst_nodes[gi]) {
                int pq = atomicAdd(&cand_cnt[gi], 1);
                if (pq < CAP) {
                  cand_val[gi * CAP + pq] = raw * invv;
                  cand_idx[gi * CAP + pq] = gj;
                }
              }
            }
          }
        }
      }
    }

    // (c) own-wave wait + convert staged tile t+1 -> frag[par^1]
    if (t + 1 < NT) QCONVERT(par ^ 1);

    // (d) barrier: frag[par^1] visible; frag[par] free at t+2
    __syncthreads();
  }
#undef QSTAGE
#undef QCONVERT
}

// ---- kernel 3: top-5 per row, threefry negatives, assemble ----
__global__ void finalize_kernel(const int* __restrict__ src_nodes,
                                const int* __restrict__ dst_nodes,
                                const float* __restrict__ labels,
                                const float* __restrict__ ts,
                                const int* __restrict__ cand_cnt,
                                const float* __restrict__ cand_val,
                                const int* __restrict__ cand_idx,
                                float* __restrict__ out) {
  int r = blockIdx.x * 256 + threadIdx.x;
  if (r >= BATCH) return;
  const int TOT = BATCH + BATCH * K_NEG;  // 6144
  int srcv = src_nodes[r];
  float tsv = ts[r];
  out[r] = (float)srcv;
  out[TOT + r] = (float)dst_nodes[r];
  float l = labels[r];
  out[2 * TOT + r] = l * 0.9f + (1.0f - l) * 0.1f;
  out[3 * TOT + r] = tsv;

  int cnt = cand_cnt[r];
  cnt = cnt < CAP ? cnt : CAP;
  float cv[CAP]; int ci[CAP];
  for (int i = 0; i < cnt; ++i) { cv[i] = cand_val[r * CAP + i]; ci[i] = cand_idx[r * CAP + i]; }

  // jax.random.split(key(42)) — partitionable/foldlike: k_i = threefry(key, 0, i)
  unsigned k1a, k1b, k2a, k2b;
  tf2x32(0u, 42u, 0u, 0u, &k1a, &k1b);
  tf2x32(0u, 42u, 0u, 1u, &k2a, &k2b);

  const unsigned span = 200000u;
  const unsigned mult = 167296u;  // 2^32 % span

  for (int s = 0; s < K_NEG; ++s) {
    int sel = -1;
    for (int i = 0; i < cnt; ++i)
      if (sel < 0 || cv[i] > cv[sel] || (cv[i] == cv[sel] && ci[i] < ci[sel])) sel = i;
    float v = FILL; int idx = 0;
    if (sel >= 0) { v = cv[sel]; idx = ci[sel]; cv[sel] = FILL; ci[sel] = 0x7fffffff; }
    bool is_real = v > (FILL + 1.0f);

    unsigned m = (unsigned)(r * K_NEG + s);
    unsigned hi = rbits32(k1a, k1b, m);
    unsigned lo = rbits32(k2a, k2b, m);
    unsigned off = ((hi % span) * mult + (lo % span)) % span;  // uint32 wrap, as JAX
    int rd = (int)off;
    if (rd == srcv) rd = (rd + 1) % NUM_NODES;
    int fd = is_real ? idx : rd;

    int mi = (int)m;
    out[BATCH + mi] = (float)srcv;
    out[TOT + BATCH + mi] = (float)fd;
    out[2 * TOT + BATCH + mi] = 0.1f;   // smoothing of label 0
    out[3 * TOT + BATCH + mi] = tsv;
    out[4 * TOT + mi] = v;
  }
}

extern "C" void kernel_launch(void* const* d_in, const int* in_sizes, int n_in,
                              void* d_out, int out_size, void* d_ws, size_t ws_size,
                              hipStream_t stream) {
  const int* src = (const int*)d_in[0];
  const int* dst = (const int*)d_in[1];
  const float* labels = (const float*)d_in[2];
  const float* ts = (const float*)d_in[3];
  const float* memory = (const float*)d_in[4];
  float* out = (float*)d_out;

  char* ws = (char*)d_ws;
  unsigned short* s16f = (unsigned short*)ws;       // 1024*128*2 = 262144 B (fragment-major)
  int* cand_cnt = (int*)(ws + 262144);              // 4096 B
  float* cand_val = (float*)(ws + 266240);          // 65536 B
  int* cand_idx = (int*)(ws + 331776);              // 65536 B

  prep_kernel<<<256, 256, 0, stream>>>(memory, src, s16f, cand_cnt);
  sim_scan_kernel<<<NBLK, 512, 0, stream>>>(memory, s16f, dst, cand_cnt, cand_val, cand_idx);
  finalize_kernel<<<(BATCH + 255) / 256, 256, 0, stream>>>(src, dst, labels, ts,
                                                           cand_cnt, cand_val, cand_idx, out);
}